// Round 5
// baseline (1187.248 us; speedup 1.0000x reference)
//
#include <hip/hip_runtime.h>
#include <math.h>

#define NB 8          // batch
#define NC 3          // channels
#define PD 192        // feature dim = 3*8*8
#define IMG 512
#define NP 169        // patches per spatial dim
#define NPATCH 28561  // NP*NP
#define INV_N (1.0f/28561.0f)

typedef float f4 __attribute__((ext_vector_type(4)));
typedef f4 f4u __attribute__((aligned(4)));   // 4B-aligned vector load type

__device__ __forceinline__ float rdlane(float v, int lane) {
  return __uint_as_float(__builtin_amdgcn_readlane(__float_as_uint(v), lane));
}

// ---------------- per-feature patch sums (for the mean) ----------------
__global__ __launch_bounds__(256) void row_sums_k(const float* __restrict__ x,
                                                  float* __restrict__ S) {
  int bid = blockIdx.x;            // b*PD + d
  int b = bid / PD, d = bid - b * PD;
  int c = d >> 6, ii = (d >> 3) & 7, jj = d & 7;
  const float* img = x + ((size_t)(b * NC + c)) * (IMG * IMG);
  float part = 0.f;
  for (int p = threadIdx.x; p < NPATCH; p += 256) {
    int ph = p / NP;
    int pw = p - ph * NP;
    part += img[(3 * ph + ii) * IMG + 3 * pw + jj];
  }
  __shared__ float red[256];
  int t = threadIdx.x;
  red[t] = part; __syncthreads();
  for (int s = 128; s > 0; s >>= 1) { if (t < s) red[t] += red[t + s]; __syncthreads(); }
  if (t == 0) S[bid] = red[0];
}

// ---------------- split-K Gram matrix: partial[chunk][b][192][192] ----------------
__global__ __launch_bounds__(256, 2) void cov_gemm_k(const float* __restrict__ x,
                                                     float* __restrict__ partial,
                                                     int CH, int chunkSize) {
  int chunk = blockIdx.x % CH;
  int b = blockIdx.x / CH;
  int p0 = chunk * chunkSize;
  int pcount = NPATCH - p0;
  if (pcount > chunkSize) pcount = chunkSize;
  if (pcount < 0) pcount = 0;
  int ntiles = (pcount + 15) >> 4;
  int pend = p0 + pcount;

  __shared__ float As[16][200];    // [k-slice][192 features + pad]

  int t = threadIdx.x;
  int ty = t >> 4, tx = t & 15;
  const float* imgb = x + (size_t)b * NC * IMG * IMG;

  float acc[12][12];
  for (int i = 0; i < 12; ++i)
    for (int j = 0; j < 12; ++j)
      acc[i][j] = 0.f;

  for (int kt = 0; kt < ntiles; ++kt) {
    int pbase = p0 + (kt << 4);
    f4 ld[3];
    int pks[3], dls[3];
#pragma unroll
    for (int l = 0; l < 3; ++l) {
      int f = l * 256 + t;          // 0..767 quad index
      int pk = f / 48;              // 0..15 patch within k-tile
      int rr = f - pk * 48;         // 0..47
      int c  = rr >> 4;             // channel
      int ii = (rr & 15) >> 1;      // patch row offset 0..7
      int j4 = (rr & 1) << 2;       // 0 or 4
      int p = pbase + pk;
      f4 v = {0.f, 0.f, 0.f, 0.f};
      if (p < pend) {
        int ph = p / NP, pw = p - ph * NP;
        const f4u* src = (const f4u*)(imgb + ((size_t)c * IMG + (3 * ph + ii)) * IMG + 3 * pw + j4);
        v = (f4)(*src);
      }
      ld[l] = v;
      pks[l] = pk;
      dls[l] = (c << 6) + (ii << 3) + j4;
    }
    __syncthreads();
#pragma unroll
    for (int l = 0; l < 3; ++l)
      *(f4*)&As[pks[l]][dls[l]] = ld[l];
    __syncthreads();

    for (int kk = 0; kk < 16; ++kk) {
      const f4* ap = (const f4*)&As[kk][ty * 12];
      const f4* bp = (const f4*)&As[kk][tx * 12];
      f4 avq[3], bvq[3];
#pragma unroll
      for (int q = 0; q < 3; ++q) { avq[q] = ap[q]; bvq[q] = bp[q]; }
      float a[12], bb[12];
#pragma unroll
      for (int q = 0; q < 12; ++q) { a[q] = avq[q >> 2][q & 3]; bb[q] = bvq[q >> 2][q & 3]; }
#pragma unroll
      for (int i = 0; i < 12; ++i)
#pragma unroll
        for (int j = 0; j < 12; ++j)
          acc[i][j] += a[i] * bb[j];
    }
  }

  float* outp = partial + ((size_t)chunk * NB + b) * PD * PD;
  for (int i = 0; i < 12; ++i) {
    int m = ty * 12 + i;
    for (int j = 0; j < 12; ++j)
      outp[m * PD + tx * 12 + j] = acc[i][j];
  }
}

// ---------------- reduce partials + finalize covariance ----------------
__global__ __launch_bounds__(256) void reduce_fin_k(const float* __restrict__ partial,
                                                    const float* __restrict__ S,
                                                    float* __restrict__ G, int CH) {
  int e = blockIdx.x * 256 + threadIdx.x;
  const int tot = NB * PD * PD;
  if (e >= tot) return;
  int b = e / (PD * PD);
  int rem = e - b * PD * PD;
  int i = rem / PD, j = rem - i * PD;
  float s = 0.f;
  for (int c = 0; c < CH; ++c) s += partial[((size_t)c * NB + b) * PD * PD + rem];
  float mui = S[b * PD + i] * INV_N, muj = S[b * PD + j] * INV_N;
  G[e] = s * INV_N - mui * muj;
}

// ---------------- eigenvalues: register-resident Householder tridiag ----------------
// v5: symmetric in-wave matvec (p for own 16 rows via 16 parallel 64-lane
// butterflies; ppw all-to-all deleted; w computed fully in-register), 3 LDS
// round-trips/step. 5-ary Sturm bisection on all 768 threads (14 rounds).
__global__ __launch_bounds__(768, 3) void eigen_k(const float* __restrict__ sigma,
                                                  float* __restrict__ out) {
  __shared__ float vvg[2][PD];      // v, double-buffered by step parity, zero-padded
  __shared__ float wwg[PD];         // w vector
  __shared__ float red0[2];         // beta per parity
  __shared__ float red2[12];        // per-wave v^T A v partials
  __shared__ float dd[PD], ee[PD], e2[PD];
  __shared__ float sig[PD], csum[PD];
  __shared__ float grd[8];
  __shared__ float scanw[4];
  __shared__ int   redi[4];
  __shared__ int   cntb[4][PD];

  int b = blockIdx.x, t = threadIdx.x;
  int w = t >> 6, l = t & 63;
  int colbase = w << 4;
  const float* M = sigma + (size_t)b * PD * PD;

  // load fragment (strided f4 global reads; matrix is L2-resident)
  f4 a[3][4];
#pragma unroll
  for (int rr = 0; rr < 3; ++rr) {
    const float* mp = M + (size_t)((rr << 6) + l) * PD + colbase;
#pragma unroll
    for (int cc = 0; cc < 4; ++cc)
      a[rr][cc] = *(const f4*)(mp + (cc << 2));
  }

  // prep(c): owning wave extracts column c (span [c+1,PD)), computes alpha/beta,
  // writes v into vvg[c&1] (full coverage: zeros below head), ee[c], red0[c&1].
  auto prep = [&](int c) {
    int wown = c >> 4;
    if (w == wown) {
      int k1 = c + 1;
      float av[3] = {0.f, 0.f, 0.f};
#pragma unroll
      for (int cc = 0; cc < 4; ++cc)
#pragma unroll
        for (int e = 0; e < 4; ++e) {
          if (colbase + (cc << 2) + e == c) {   // wave-uniform guard
            av[0] = a[0][cc][e]; av[1] = a[1][cc][e]; av[2] = a[2][cc][e];
          }
        }
      float am[3];
#pragma unroll
      for (int rr = 0; rr < 3; ++rr) {
        int row = (rr << 6) + l;
        am[rr] = (row >= k1) ? av[rr] : 0.f;
      }
      float sq = am[0] * am[0] + am[1] * am[1] + am[2] * am[2];
#pragma unroll
      for (int off = 32; off; off >>= 1) sq += __shfl_xor(sq, off, 64);
      int slot = k1 >> 6;                        // uniform
      float tmp = (slot == 0) ? av[0] : (slot == 1) ? av[1] : av[2];
      float x0 = rdlane(tmp, k1 & 63);
      float nrm = sqrtf(sq);
      float alpha = (x0 >= 0.f) ? -nrm : nrm;
      bool degen = (sq < 1e-32f);
      float beta = degen ? 0.f : 1.0f / (sq - alpha * x0);
      int par = c & 1;
      if (l == 0) {
        red0[par] = beta;
        ee[c] = degen ? x0 : alpha;
      }
      float head = x0 - alpha;
#pragma unroll
      for (int rr = 0; rr < 3; ++rr) {
        int row = (rr << 6) + l;
        vvg[par][row] = (row < k1) ? 0.f : (row == k1) ? head : am[rr];
      }
    }
  };

  prep(0);
  __syncthreads();

  int slot = w >> 2;                 // wave-uniform
  int lbase = (w & 3) << 4;

  for (int k = 0; k < PD - 2; ++k) {
    int cur = k & 1;
    int k1 = k + 1;
    bool wact = (colbase + 15) >= k1;           // wave-uniform col retirement

    float vr[3] = {0.f, 0.f, 0.f};
    float sv[16], pj[16], wj[16];
#pragma unroll
    for (int j = 0; j < 16; ++j) { sv[j] = 0.f; pj[j] = 0.f; }

    // ---- Phase A: p (own 16 rows, via symmetry) + v^T A v partial ----
    if (wact) {
#pragma unroll
      for (int rr = 0; rr < 3; ++rr) vr[rr] = vvg[cur][(rr << 6) + l];
      {
        float src = (slot == 0) ? vr[0] : (slot == 1) ? vr[1] : vr[2];
#pragma unroll
        for (int j = 0; j < 16; ++j) sv[j] = rdlane(src, lbase + j);
      }
#pragma unroll
      for (int rr = 0; rr < 3; ++rr) {
        if ((rr << 6) + 63 >= k1) {              // row-block retirement
          float vrr = vr[rr];
#pragma unroll
          for (int cc = 0; cc < 4; ++cc)
#pragma unroll
            for (int e = 0; e < 4; ++e)
              pj[(cc << 2) + e] += vrr * a[rr][cc][e];
        }
      }
      // 16 simultaneous 64-lane butterflies -> every lane holds full p_j
#pragma unroll
      for (int off = 1; off < 64; off <<= 1) {
#pragma unroll
        for (int j = 0; j < 16; ++j) pj[j] += __shfl_xor(pj[j], off, 64);
      }
      float dp = 0.f;
#pragma unroll
      for (int j = 0; j < 16; ++j) dp += sv[j] * pj[j];
      if (l == 0) red2[w] = dp;
    } else if (l == 0) red2[w] = 0.f;
    __syncthreads();                             // B1

    // ---- Phase B: w for own 16 rows, fully in-register ----
    {
      float beta = red0[cur];
      float vt = 0.f;
#pragma unroll
      for (int j = 0; j < 12; ++j) vt += red2[j];
      float Kc = 0.5f * beta * beta * vt;
#pragma unroll
      for (int j = 0; j < 16; ++j) {
        float wv = beta * pj[j] - Kc * sv[j];
        wj[j] = (wact && (colbase + j >= k1)) ? wv : 0.f;
      }
      if (l < 16) {
        float val = 0.f;
#pragma unroll
        for (int j = 0; j < 16; ++j) if (l == j) val = wj[j];
        wwg[colbase + l] = val;
      }
    }
    __syncthreads();                             // B2

    // ---- Phase C: rank-2 update (sv/wj already in registers) ----
    if (wact) {
      float wr[3];
#pragma unroll
      for (int rr = 0; rr < 3; ++rr) wr[rr] = wwg[(rr << 6) + l];
#pragma unroll
      for (int rr = 0; rr < 3; ++rr) {
        if ((rr << 6) + 63 >= k1) {
          float vrr = vr[rr], wrr = wr[rr];
#pragma unroll
          for (int cc = 0; cc < 4; ++cc)
#pragma unroll
            for (int e = 0; e < 4; ++e) {
              int j = (cc << 2) + e;
              a[rr][cc][e] -= vrr * wj[j] + wrr * sv[j];
            }
        }
      }
    }
    prep(k + 1);                                 // owner wave is always col-active
    __syncthreads();                             // B3
  }

  // ---- extract diagonal ----
#pragma unroll
  for (int rr = 0; rr < 3; ++rr) {
    int row = (rr << 6) + l;
#pragma unroll
    for (int cc = 0; cc < 4; ++cc)
#pragma unroll
      for (int e = 0; e < 4; ++e)
        if (colbase + (cc << 2) + e == row) dd[row] = a[rr][cc][e];
  }
  __syncthreads();

  if (t < PD - 1) e2[t] = ee[t] * ee[t];

  // Gershgorin bounds
  float glo = 1e30f, ghi = -1e30f;
  if (t < PD) {
    float r = 0.f;
    if (t > 0) r += fabsf(ee[t - 1]);
    if (t < PD - 1) r += fabsf(ee[t]);
    glo = dd[t] - r;
    ghi = dd[t] + r;
  }
#pragma unroll
  for (int off = 32; off; off >>= 1) {
    glo = fminf(glo, __shfl_xor(glo, off, 64));
    ghi = fmaxf(ghi, __shfl_xor(ghi, off, 64));
  }
  if (l == 0 && w < 3) { grd[w] = glo; grd[4 + w] = ghi; }
  __syncthreads();
  float gl = fminf(grd[0], fminf(grd[1], grd[2]));
  float gh = fmaxf(grd[4], fmaxf(grd[5], grd[6]));
  float wid = gh - gl;
  gl -= 1e-3f * wid + 1e-20f;
  gh += 1e-3f * wid + 1e-20f;

  // ---- 5-ary Sturm bisection: 4 probe threads per eigenvalue ----
  {
    int we3 = w - (w / 3) * 3;                  // w % 3
    int sub = w / 3;                            // 0..3
    int e = (we3 << 6) + l;                     // eigenvalue index 0..191
    float lo = gl, hi = gh;
    for (int round = 0; round < 14; ++round) {
      float width = hi - lo;
      float xm = lo + width * (0.2f * (float)(sub + 1));
      int cnt = 0;
      float q = 1.0f;
      for (int i = 0; i < PD; ++i) {
        float term = (i > 0) ? e2[i - 1] * __builtin_amdgcn_rcpf(q) : 0.0f;
        q = (dd[i] - xm) - term;
        cnt += (q < 0.f);
        float aq = fabsf(q);
        if (aq < 1e-30f) q = (q < 0.f) ? -1e-30f : 1e-30f;
      }
      cntb[sub][e] = cnt;
      __syncthreads();
      int c0 = cntb[0][e], c1 = cntb[1][e], c2 = cntb[2][e], c3 = cntb[3][e];
      float mA = lo + width * 0.2f, mB = lo + width * 0.4f;
      float mC = lo + width * 0.6f, mD = lo + width * 0.8f;
      float nl = lo, nh = hi;
      if (c0 <= e) nl = mA;
      if (c1 <= e) nl = mB;
      if (c2 <= e) nl = mC;
      if (c3 <= e) nl = mD;
      if (c3 > e) nh = mD;
      if (c2 > e) nh = mC;
      if (c1 > e) nh = mB;
      if (c0 > e) nh = mA;
      lo = nl; hi = nh;
      __syncthreads();
    }
    if (sub == 0) sig[e] = 0.5f * (lo + hi);
  }
  __syncthreads();

  // parallel inclusive scan of sig -> csum (threads<192)
  {
    float x = (t < PD) ? sig[t] : 0.f;
    float scn = x;
#pragma unroll
    for (int off = 1; off < 64; off <<= 1) {
      float u = __shfl_up(scn, off, 64);
      if (l >= off) scn += u;
    }
    if (l == 63 && w < 3) scanw[w] = scn;
    __syncthreads();
    if (t < PD) {
      float base = 0.f;
      if (w >= 1) base += scanw[0];
      if (w >= 2) base += scanw[1];
      csum[t] = scn + base;
    }
  }
  __syncthreads();

  // threshold search (mirror of the reference's vectorized loop)
  float tau = 0.f;
  int vk = 1 << 30;
  if (t < PD) {
    int L = PD - 1 - t;
    tau = (L > 0) ? csum[L - 1] / (float)L : 0.0f;
    int gt = 0, lt2 = 0;
    for (int j = 0; j < L; ++j) {
      float svv = sig[j];
      gt  += (svv > tau);
      lt2 += (svv < tau);
    }
    if (gt == lt2) vk = t;
  }
#pragma unroll
  for (int off = 32; off; off >>= 1) vk = min(vk, __shfl_xor(vk, off, 64));
  if (l == 0 && w < 3) redi[w] = vk;
  __syncthreads();
  if (t == 0) {
    int g = min(redi[0], min(redi[1], redi[2]));
    redi[3] = (g == (1 << 30)) ? 0 : g;   // reference: argmax of all-false = 0
  }
  __syncthreads();
  if (t < PD && t == redi[3]) out[b] = sqrtf(fmaxf(tau, 0.f));
}

extern "C" void kernel_launch(void* const* d_in, const int* in_sizes, int n_in,
                              void* d_out, int out_size, void* d_ws, size_t ws_size,
                              hipStream_t stream) {
  const float* x = (const float*)d_in[0];
  float* out = (float*)d_out;

  size_t gElems = (size_t)NB * PD * PD;       // 294912
  int CH = 64;
  while (CH > 1 && ws_size < ((size_t)CH + 1) * gElems * 4 + (size_t)NB * PD * 4)
    CH >>= 1;
  float* G = (float*)d_ws;
  float* partial = G + gElems;
  float* S = partial + (size_t)CH * gElems;
  int chunkSize = (NPATCH + CH - 1) / CH;

  row_sums_k<<<NB * PD, 256, 0, stream>>>(x, S);
  cov_gemm_k<<<NB * CH, 256, 0, stream>>>(x, partial, CH, chunkSize);
  reduce_fin_k<<<(int)((gElems + 255) / 256), 256, 0, stream>>>(partial, S, G, CH);
  eigen_k<<<NB, 768, 0, stream>>>(G, out);
}

// Round 6
// 816.574 us; speedup vs baseline: 1.4539x; 1.4539x over previous
//
#include <hip/hip_runtime.h>
#include <math.h>

#define NB 8          // batch
#define NC 3          // channels
#define PD 192        // feature dim = 3*8*8
#define IMG 512
#define NP 169        // patches per spatial dim
#define NPATCH 28561  // NP*NP
#define INV_N (1.0f/28561.0f)

typedef float f4 __attribute__((ext_vector_type(4)));
typedef f4 f4u __attribute__((aligned(4)));   // 4B-aligned vector load type

__device__ __forceinline__ float rdlane(float v, int lane) {
  return __uint_as_float(__builtin_amdgcn_readlane(__float_as_uint(v), lane));
}

// DPP-based add of a shifted copy (VALU, no LDS pipe).
template<int CTRL, int RM, int BM>
__device__ __forceinline__ float dpp_add(float x) {
  int sh = __builtin_amdgcn_update_dpp(0, __float_as_int(x), CTRL, RM, BM, false);
  return x + __int_as_float(sh);
}
// sum over all 64 lanes -> scalar (uniform)
__device__ __forceinline__ float wave_sum(float x) {
  x = dpp_add<0x111, 0xF, 0xF>(x);   // row_shr:1
  x = dpp_add<0x112, 0xF, 0xF>(x);   // row_shr:2
  x = dpp_add<0x114, 0xF, 0xF>(x);   // row_shr:4
  x = dpp_add<0x118, 0xF, 0xF>(x);   // row_shr:8
  x = dpp_add<0x142, 0xA, 0xF>(x);   // row_bcast:15 -> rows 1,3
  x = dpp_add<0x143, 0xC, 0xF>(x);   // row_bcast:31 -> rows 2,3
  return rdlane(x, 63);
}
// sum over lanes 0..15 (same data replicated per 16-row) -> scalar
__device__ __forceinline__ float row16_sum(float x) {
  x = dpp_add<0x111, 0xF, 0xF>(x);
  x = dpp_add<0x112, 0xF, 0xF>(x);
  x = dpp_add<0x114, 0xF, 0xF>(x);
  x = dpp_add<0x118, 0xF, 0xF>(x);
  return rdlane(x, 15);
}

// ---------------- per-feature patch sums (for the mean) ----------------
__global__ __launch_bounds__(256) void row_sums_k(const float* __restrict__ x,
                                                  float* __restrict__ S) {
  int bid = blockIdx.x;            // b*PD + d
  int b = bid / PD, d = bid - b * PD;
  int c = d >> 6, ii = (d >> 3) & 7, jj = d & 7;
  const float* img = x + ((size_t)(b * NC + c)) * (IMG * IMG);
  float part = 0.f;
  for (int p = threadIdx.x; p < NPATCH; p += 256) {
    int ph = p / NP;
    int pw = p - ph * NP;
    part += img[(3 * ph + ii) * IMG + 3 * pw + jj];
  }
  __shared__ float red[256];
  int t = threadIdx.x;
  red[t] = part; __syncthreads();
  for (int s = 128; s > 0; s >>= 1) { if (t < s) red[t] += red[t + s]; __syncthreads(); }
  if (t == 0) S[bid] = red[0];
}

// ---------------- split-K Gram matrix: partial[chunk][b][192][192] ----------------
__global__ __launch_bounds__(256, 2) void cov_gemm_k(const float* __restrict__ x,
                                                     float* __restrict__ partial,
                                                     int CH, int chunkSize) {
  int chunk = blockIdx.x % CH;
  int b = blockIdx.x / CH;
  int p0 = chunk * chunkSize;
  int pcount = NPATCH - p0;
  if (pcount > chunkSize) pcount = chunkSize;
  if (pcount < 0) pcount = 0;
  int ntiles = (pcount + 15) >> 4;
  int pend = p0 + pcount;

  __shared__ float As[16][200];    // [k-slice][192 features + pad]

  int t = threadIdx.x;
  int ty = t >> 4, tx = t & 15;
  const float* imgb = x + (size_t)b * NC * IMG * IMG;

  float acc[12][12];
  for (int i = 0; i < 12; ++i)
    for (int j = 0; j < 12; ++j)
      acc[i][j] = 0.f;

  for (int kt = 0; kt < ntiles; ++kt) {
    int pbase = p0 + (kt << 4);
    f4 ld[3];
    int pks[3], dls[3];
#pragma unroll
    for (int l = 0; l < 3; ++l) {
      int f = l * 256 + t;          // 0..767 quad index
      int pk = f / 48;              // 0..15 patch within k-tile
      int rr = f - pk * 48;         // 0..47
      int c  = rr >> 4;             // channel
      int ii = (rr & 15) >> 1;      // patch row offset 0..7
      int j4 = (rr & 1) << 2;       // 0 or 4
      int p = pbase + pk;
      f4 v = {0.f, 0.f, 0.f, 0.f};
      if (p < pend) {
        int ph = p / NP, pw = p - ph * NP;
        const f4u* src = (const f4u*)(imgb + ((size_t)c * IMG + (3 * ph + ii)) * IMG + 3 * pw + j4);
        v = (f4)(*src);
      }
      ld[l] = v;
      pks[l] = pk;
      dls[l] = (c << 6) + (ii << 3) + j4;
    }
    __syncthreads();
#pragma unroll
    for (int l = 0; l < 3; ++l)
      *(f4*)&As[pks[l]][dls[l]] = ld[l];
    __syncthreads();

    for (int kk = 0; kk < 16; ++kk) {
      const f4* ap = (const f4*)&As[kk][ty * 12];
      const f4* bp = (const f4*)&As[kk][tx * 12];
      f4 avq[3], bvq[3];
#pragma unroll
      for (int q = 0; q < 3; ++q) { avq[q] = ap[q]; bvq[q] = bp[q]; }
      float a[12], bb[12];
#pragma unroll
      for (int q = 0; q < 12; ++q) { a[q] = avq[q >> 2][q & 3]; bb[q] = bvq[q >> 2][q & 3]; }
#pragma unroll
      for (int i = 0; i < 12; ++i)
#pragma unroll
        for (int j = 0; j < 12; ++j)
          acc[i][j] += a[i] * bb[j];
    }
  }

  float* outp = partial + ((size_t)chunk * NB + b) * PD * PD;
  for (int i = 0; i < 12; ++i) {
    int m = ty * 12 + i;
    for (int j = 0; j < 12; ++j)
      outp[m * PD + tx * 12 + j] = acc[i][j];
  }
}

// ---------------- reduce partials + finalize covariance ----------------
__global__ __launch_bounds__(256) void reduce_fin_k(const float* __restrict__ partial,
                                                    const float* __restrict__ S,
                                                    float* __restrict__ G, int CH) {
  int e = blockIdx.x * 256 + threadIdx.x;
  const int tot = NB * PD * PD;
  if (e >= tot) return;
  int b = e / (PD * PD);
  int rem = e - b * PD * PD;
  int i = rem / PD, j = rem - i * PD;
  float s = 0.f;
  for (int c = 0; c < CH; ++c) s += partial[((size_t)c * NB + b) * PD * PD + rem];
  float mui = S[b * PD + i] * INV_N, muj = S[b * PD + j] * INV_N;
  G[e] = s * INV_N - mui * muj;
}

// ---------------- eigenvalues: register-resident Householder tridiag ----------------
// v6: v4 ppw structure + DPP reductions (DS-free), conflict-free padded ppw,
// simplified phase B' (12 direct broadcast reads), 5-ary bisection.
#define PPL 196   // ppw row stride (mod 32 = 4 -> decorrelates slices)
__global__ __launch_bounds__(768, 3) void eigen_k(const float* __restrict__ sigma,
                                                  float* __restrict__ out) {
  __shared__ float ppw[12][PPL];    // per-wave matvec partials (unscaled)
  __shared__ float vvg[2][PD];      // v, double-buffered by step parity, zero-padded
  __shared__ float wwg[PD];         // w vector
  __shared__ float red0[2];         // beta per parity
  __shared__ float red2[16];        // per-wave v^T A v partials (12 used + 4 zeros)
  __shared__ float dd[PD], ee[PD], e2[PD];
  __shared__ float sig[PD], csum[PD];
  __shared__ float grd[8];
  __shared__ float scanw[4];
  __shared__ int   redi[4];
  __shared__ int   cntb[4][PD];

  int b = blockIdx.x, t = threadIdx.x;
  int w = t >> 6, l = t & 63;
  int colbase = w << 4;
  const float* M = sigma + (size_t)b * PD * PD;

  // load fragment (strided f4 global reads; matrix is L2-resident)
  f4 a[3][4];
#pragma unroll
  for (int rr = 0; rr < 3; ++rr) {
    const float* mp = M + (size_t)((rr << 6) + l) * PD + colbase;
#pragma unroll
    for (int cc = 0; cc < 4; ++cc)
      a[rr][cc] = *(const f4*)(mp + (cc << 2));
  }
  if (t >= 12 && t < 16) red2[t] = 0.f;

  // prep(c): owning wave extracts column c (span [c+1,PD)), computes alpha/beta,
  // writes v into vvg[c&1] (full coverage: zeros below head), ee[c], red0[c&1].
  auto prep = [&](int c) {
    int wown = c >> 4;
    if (w == wown) {
      int k1 = c + 1;
      float av[3] = {0.f, 0.f, 0.f};
#pragma unroll
      for (int cc = 0; cc < 4; ++cc)
#pragma unroll
        for (int e = 0; e < 4; ++e) {
          if (colbase + (cc << 2) + e == c) {   // wave-uniform guard
            av[0] = a[0][cc][e]; av[1] = a[1][cc][e]; av[2] = a[2][cc][e];
          }
        }
      float am[3];
#pragma unroll
      for (int rr = 0; rr < 3; ++rr) {
        int row = (rr << 6) + l;
        am[rr] = (row >= k1) ? av[rr] : 0.f;
      }
      float sq = wave_sum(am[0] * am[0] + am[1] * am[1] + am[2] * am[2]);
      int slot = k1 >> 6;                        // uniform
      float tmp = (slot == 0) ? av[0] : (slot == 1) ? av[1] : av[2];
      float x0 = rdlane(tmp, k1 & 63);
      float nrm = sqrtf(sq);
      float alpha = (x0 >= 0.f) ? -nrm : nrm;
      bool degen = (sq < 1e-32f);
      float beta = degen ? 0.f : 1.0f / (sq - alpha * x0);
      if (l == 0) {
        red0[c & 1] = beta;
        ee[c] = degen ? x0 : alpha;
      }
      float head = x0 - alpha;
#pragma unroll
      for (int rr = 0; rr < 3; ++rr) {
        int row = (rr << 6) + l;
        vvg[c & 1][row] = (row < k1) ? 0.f : (row == k1) ? head : am[rr];
      }
    }
  };

  prep(0);
  __syncthreads();

  int slot = w >> 2;                 // wave-uniform
  int lbase = (w & 3) << 4;

  for (int k = 0; k < PD - 2; ++k) {
    int cur = k & 1;
    int k1 = k + 1;
    int j0 = k1 >> 4;                           // first col-active wave
    bool wact = (colbase + 15) >= k1;           // wave-uniform col retirement

    float vr[3] = {0.f, 0.f, 0.f};
    float sv[16];

    // ---- Phase A: ppw[w] = A_slice * v; red2[w] = v^T A_slice v (DPP) ----
    if (wact) {
#pragma unroll
      for (int rr = 0; rr < 3; ++rr) vr[rr] = vvg[cur][(rr << 6) + l];
      {
        float src = (slot == 0) ? vr[0] : (slot == 1) ? vr[1] : vr[2];
#pragma unroll
        for (int j = 0; j < 16; ++j) sv[j] = rdlane(src, lbase + j);
      }
      float dp = 0.f;
#pragma unroll
      for (int rr = 0; rr < 3; ++rr) {
        if ((rr << 6) + 63 >= k1) {              // row-block retirement
          f4 s4 = {0.f, 0.f, 0.f, 0.f};
#pragma unroll
          for (int cc = 0; cc < 4; ++cc) {
            f4 sva = {sv[(cc << 2)], sv[(cc << 2) + 1], sv[(cc << 2) + 2], sv[(cc << 2) + 3]};
            s4 += sva * a[rr][cc];
          }
          float s = (s4.x + s4.y) + (s4.z + s4.w);
          ppw[w][(rr << 6) + l] = s;
          dp += vr[rr] * s;
        }
      }
      float dpt = wave_sum(dp);
      if (l == 0) red2[w] = dpt;
    } else if (l == 0) red2[w] = 0.f;
    __syncthreads();                             // B1

    // ---- Phase B': w for this wave's 16 rows (12 direct reads, DPP vt) ----
    {
      float rv = red2[l & 15];                   // broadcast read (12 real + 4 zero)
      float vt = row16_sum(rv);                  // scalar v^T A v
      if (l < 16) {
        int row = colbase + l;
        float s = 0.f;
#pragma unroll
        for (int j = 0; j < 12; ++j) {
          float pv = ppw[j][row];
          s += (j >= j0) ? pv : 0.f;             // mask stale retired slices
        }
        float beta = red0[cur];
        float Kc = 0.5f * beta * beta * vt;
        float vown = vvg[cur][row];
        wwg[row] = (row >= k1) ? (beta * s - Kc * vown) : 0.f;
      }
    }
    __syncthreads();                             // B2

    // ---- Phase C: rank-2 update (registers) + prep next column ----
    if (wact) {
      float wr[3], sw[16];
#pragma unroll
      for (int rr = 0; rr < 3; ++rr) wr[rr] = wwg[(rr << 6) + l];
      {
        float srcw = (slot == 0) ? wr[0] : (slot == 1) ? wr[1] : wr[2];
#pragma unroll
        for (int j = 0; j < 16; ++j) sw[j] = rdlane(srcw, lbase + j);
      }
#pragma unroll
      for (int rr = 0; rr < 3; ++rr) {
        if ((rr << 6) + 63 >= k1) {
          float vrr = vr[rr], wrr = wr[rr];
#pragma unroll
          for (int cc = 0; cc < 4; ++cc)
#pragma unroll
            for (int e = 0; e < 4; ++e) {
              int j = (cc << 2) + e;
              a[rr][cc][e] -= vrr * sw[j] + wrr * sv[j];
            }
        }
      }
    }
    prep(k + 1);                                 // owner wave is always col-active
    __syncthreads();                             // B3
  }

  // ---- extract diagonal ----
#pragma unroll
  for (int rr = 0; rr < 3; ++rr) {
    int row = (rr << 6) + l;
#pragma unroll
    for (int cc = 0; cc < 4; ++cc)
#pragma unroll
      for (int e = 0; e < 4; ++e)
        if (colbase + (cc << 2) + e == row) dd[row] = a[rr][cc][e];
  }
  __syncthreads();

  if (t < PD - 1) e2[t] = ee[t] * ee[t];

  // Gershgorin bounds
  float glo = 1e30f, ghi = -1e30f;
  if (t < PD) {
    float r = 0.f;
    if (t > 0) r += fabsf(ee[t - 1]);
    if (t < PD - 1) r += fabsf(ee[t]);
    glo = dd[t] - r;
    ghi = dd[t] + r;
  }
#pragma unroll
  for (int off = 32; off; off >>= 1) {
    glo = fminf(glo, __shfl_xor(glo, off, 64));
    ghi = fmaxf(ghi, __shfl_xor(ghi, off, 64));
  }
  if (l == 0 && w < 3) { grd[w] = glo; grd[4 + w] = ghi; }
  __syncthreads();
  float gl = fminf(grd[0], fminf(grd[1], grd[2]));
  float gh = fmaxf(grd[4], fmaxf(grd[5], grd[6]));
  float wid = gh - gl;
  gl -= 1e-3f * wid + 1e-20f;
  gh += 1e-3f * wid + 1e-20f;

  // ---- 5-ary Sturm bisection: 4 probe threads per eigenvalue ----
  {
    int we3 = w - (w / 3) * 3;                  // w % 3
    int sub = w / 3;                            // 0..3
    int e = (we3 << 6) + l;                     // eigenvalue index 0..191
    float lo = gl, hi = gh;
    for (int round = 0; round < 14; ++round) {
      float width = hi - lo;
      float xm = lo + width * (0.2f * (float)(sub + 1));
      int cnt = 0;
      float q = 1.0f;
      for (int i = 0; i < PD; ++i) {
        float term = (i > 0) ? e2[i - 1] * __builtin_amdgcn_rcpf(q) : 0.0f;
        q = (dd[i] - xm) - term;
        cnt += (q < 0.f);
        float aq = fabsf(q);
        if (aq < 1e-30f) q = (q < 0.f) ? -1e-30f : 1e-30f;
      }
      cntb[sub][e] = cnt;
      __syncthreads();
      int c0 = cntb[0][e], c1 = cntb[1][e], c2 = cntb[2][e], c3 = cntb[3][e];
      float mA = lo + width * 0.2f, mB = lo + width * 0.4f;
      float mC = lo + width * 0.6f, mD = lo + width * 0.8f;
      float nl = lo, nh = hi;
      if (c0 <= e) nl = mA;
      if (c1 <= e) nl = mB;
      if (c2 <= e) nl = mC;
      if (c3 <= e) nl = mD;
      if (c3 > e) nh = mD;
      if (c2 > e) nh = mC;
      if (c1 > e) nh = mB;
      if (c0 > e) nh = mA;
      lo = nl; hi = nh;
      __syncthreads();
    }
    if (sub == 0) sig[e] = 0.5f * (lo + hi);
  }
  __syncthreads();

  // parallel inclusive scan of sig -> csum (threads<192)
  {
    float x = (t < PD) ? sig[t] : 0.f;
    float scn = x;
#pragma unroll
    for (int off = 1; off < 64; off <<= 1) {
      float u = __shfl_up(scn, off, 64);
      if (l >= off) scn += u;
    }
    if (l == 63 && w < 3) scanw[w] = scn;
    __syncthreads();
    if (t < PD) {
      float base = 0.f;
      if (w >= 1) base += scanw[0];
      if (w >= 2) base += scanw[1];
      csum[t] = scn + base;
    }
  }
  __syncthreads();

  // threshold search (mirror of the reference's vectorized loop)
  float tau = 0.f;
  int vk = 1 << 30;
  if (t < PD) {
    int L = PD - 1 - t;
    tau = (L > 0) ? csum[L - 1] / (float)L : 0.0f;
    int gt = 0, lt2 = 0;
    for (int j = 0; j < L; ++j) {
      float svv = sig[j];
      gt  += (svv > tau);
      lt2 += (svv < tau);
    }
    if (gt == lt2) vk = t;
  }
#pragma unroll
  for (int off = 32; off; off >>= 1) vk = min(vk, __shfl_xor(vk, off, 64));
  if (l == 0 && w < 3) redi[w] = vk;
  __syncthreads();
  if (t == 0) {
    int g = min(redi[0], min(redi[1], redi[2]));
    redi[3] = (g == (1 << 30)) ? 0 : g;   // reference: argmax of all-false = 0
  }
  __syncthreads();
  if (t < PD && t == redi[3]) out[b] = sqrtf(fmaxf(tau, 0.f));
}

extern "C" void kernel_launch(void* const* d_in, const int* in_sizes, int n_in,
                              void* d_out, int out_size, void* d_ws, size_t ws_size,
                              hipStream_t stream) {
  const float* x = (const float*)d_in[0];
  float* out = (float*)d_out;

  size_t gElems = (size_t)NB * PD * PD;       // 294912
  int CH = 64;
  while (CH > 1 && ws_size < ((size_t)CH + 1) * gElems * 4 + (size_t)NB * PD * 4)
    CH >>= 1;
  float* G = (float*)d_ws;
  float* partial = G + gElems;
  float* S = partial + (size_t)CH * gElems;
  int chunkSize = (NPATCH + CH - 1) / CH;

  row_sums_k<<<NB * PD, 256, 0, stream>>>(x, S);
  cov_gemm_k<<<NB * CH, 256, 0, stream>>>(x, partial, CH, chunkSize);
  reduce_fin_k<<<(int)((gElems + 255) / 256), 256, 0, stream>>>(partial, S, G, CH);
  eigen_k<<<NB, 768, 0, stream>>>(G, out);
}

// Round 7
// 814.179 us; speedup vs baseline: 1.4582x; 1.0029x over previous
//
#include <hip/hip_runtime.h>
#include <math.h>

#define NB 8          // batch
#define NC 3          // channels
#define PD 192        // feature dim = 3*8*8
#define IMG 512
#define NP 169        // patches per spatial dim
#define NPATCH 28561  // NP*NP
#define INV_N (1.0f/28561.0f)
#define KST 32        // GEMM K-step (patches per MFMA tile)

typedef float f4 __attribute__((ext_vector_type(4)));
typedef __bf16 bf16x8 __attribute__((ext_vector_type(8)));
typedef float f32x4 __attribute__((ext_vector_type(4)));

__device__ __forceinline__ float rdlane(float v, int lane) {
  return __uint_as_float(__builtin_amdgcn_readlane(__float_as_uint(v), lane));
}

// DPP-based add of a shifted copy (VALU, no LDS pipe).
template<int CTRL, int RM, int BM>
__device__ __forceinline__ float dpp_add(float x) {
  int sh = __builtin_amdgcn_update_dpp(0, __float_as_int(x), CTRL, RM, BM, false);
  return x + __int_as_float(sh);
}
// sum over all 64 lanes -> scalar (uniform)
__device__ __forceinline__ float wave_sum(float x) {
  x = dpp_add<0x111, 0xF, 0xF>(x);   // row_shr:1
  x = dpp_add<0x112, 0xF, 0xF>(x);   // row_shr:2
  x = dpp_add<0x114, 0xF, 0xF>(x);   // row_shr:4
  x = dpp_add<0x118, 0xF, 0xF>(x);   // row_shr:8
  x = dpp_add<0x142, 0xA, 0xF>(x);   // row_bcast:15 -> rows 1,3
  x = dpp_add<0x143, 0xC, 0xF>(x);   // row_bcast:31 -> rows 2,3
  return rdlane(x, 63);
}

// RNE float->bf16 bits
__device__ __forceinline__ unsigned bfh(float v) {
  unsigned u = __float_as_uint(v);
  return (u + 0x7FFFu + ((u >> 16) & 1u)) >> 16;
}

// ---------------- per-feature patch sums (for the mean) ----------------
__global__ __launch_bounds__(256) void row_sums_k(const float* __restrict__ x,
                                                  float* __restrict__ S) {
  int bid = blockIdx.x;            // b*PD + d
  int b = bid / PD, d = bid - b * PD;
  int c = d >> 6, ii = (d >> 3) & 7, jj = d & 7;
  const float* img = x + ((size_t)(b * NC + c)) * (IMG * IMG);
  float part = 0.f;
  for (int p = threadIdx.x; p < NPATCH; p += 256) {
    int ph = p / NP;
    int pw = p - ph * NP;
    part += img[(3 * ph + ii) * IMG + 3 * pw + jj];
  }
  __shared__ float red[256];
  int t = threadIdx.x;
  red[t] = part; __syncthreads();
  for (int s = 128; s > 0; s >>= 1) { if (t < s) red[t] += red[t + s]; __syncthreads(); }
  if (t == 0) S[bid] = red[0];
}

// ---------------- split-K Gram via bf16-split MFMA ----------------
// G = H.H^T + H.L^T + L.H^T (L.L^T ~1e-6 rel, dropped). 8 waves; wave (wr,wc)
// owns a 96x48 output patch = 6x3 16x16 tiles. LDS tiles [192][32+8pad] bf16.
__global__ __launch_bounds__(512) void cov_gemm_k(const float* __restrict__ x,
                                                  float* __restrict__ partial,
                                                  int CH, int chunkSize) {
  int chunk = blockIdx.x % CH;
  int b = blockIdx.x / CH;
  int p0 = chunk * chunkSize;
  int pcount = NPATCH - p0;
  if (pcount > chunkSize) pcount = chunkSize;
  if (pcount < 0) pcount = 0;
  int nkt = (pcount + KST - 1) / KST;
  int pend = p0 + pcount;

  __shared__ unsigned short hiT[PD * 40];   // row stride 40 ushorts = 80B
  __shared__ unsigned short loT[PD * 40];

  int t = threadIdx.x;
  int l = t & 63, w = t >> 6;
  int wr = w >> 2, wc = w & 3;
  int m0 = wr * 96, n0 = wc * 48;
  const float* imgb = x + (size_t)b * NC * IMG * IMG;

  f32x4 acc[6][3];
#pragma unroll
  for (int i = 0; i < 6; ++i)
#pragma unroll
    for (int j = 0; j < 3; ++j)
      acc[i][j] = (f32x4){0.f, 0.f, 0.f, 0.f};

  int krow = (l >> 4) << 3;   // ushort k-offset: 0,8,16,24
  int rsel = l & 15;

  for (int kt = 0; kt < nkt; ++kt) {
    int pbase = p0 + kt * KST;
    // ---- stage 32 patches x 192 features, split to hi/lo bf16 ----
#pragma unroll
    for (int s = 0; s < 6; ++s) {
      int idx = (s << 9) + t;          // 0..3071
      int f = idx >> 4, p2 = idx & 15;
      int c = f >> 6, ii = (f >> 3) & 7, jj = f & 7;
      const float* imgc = imgb + (size_t)c * IMG * IMG;
      int P0 = pbase + (p2 << 1);
      float v0 = 0.f, v1 = 0.f;
      if (P0 < pend) { int ph = P0 / NP, pw = P0 - ph * NP; v0 = imgc[(3 * ph + ii) * IMG + 3 * pw + jj]; }
      if (P0 + 1 < pend) { int ph = (P0 + 1) / NP, pw = (P0 + 1) - ph * NP; v1 = imgc[(3 * ph + ii) * IMG + 3 * pw + jj]; }
      unsigned h0 = bfh(v0), h1 = bfh(v1);
      float r0 = v0 - __uint_as_float(h0 << 16);
      float r1 = v1 - __uint_as_float(h1 << 16);
      unsigned g0 = bfh(r0), g1 = bfh(r1);
      *(unsigned*)&hiT[f * 40 + (p2 << 1)] = h0 | (h1 << 16);
      *(unsigned*)&loT[f * 40 + (p2 << 1)] = g0 | (g1 << 16);
    }
    __syncthreads();

    bf16x8 ah[6], al[6], bh[3], bl[3];
#pragma unroll
    for (int i = 0; i < 6; ++i) {
      int row = m0 + i * 16 + rsel;
      ah[i] = *(const bf16x8*)&hiT[row * 40 + krow];
      al[i] = *(const bf16x8*)&loT[row * 40 + krow];
    }
#pragma unroll
    for (int j = 0; j < 3; ++j) {
      int row = n0 + j * 16 + rsel;
      bh[j] = *(const bf16x8*)&hiT[row * 40 + krow];
      bl[j] = *(const bf16x8*)&loT[row * 40 + krow];
    }
#pragma unroll
    for (int i = 0; i < 6; ++i)
#pragma unroll
      for (int j = 0; j < 3; ++j) {
        acc[i][j] = __builtin_amdgcn_mfma_f32_16x16x32_bf16(ah[i], bh[j], acc[i][j], 0, 0, 0);
        acc[i][j] = __builtin_amdgcn_mfma_f32_16x16x32_bf16(ah[i], bl[j], acc[i][j], 0, 0, 0);
        acc[i][j] = __builtin_amdgcn_mfma_f32_16x16x32_bf16(al[i], bh[j], acc[i][j], 0, 0, 0);
      }
    __syncthreads();
  }

  float* outp = partial + ((size_t)chunk * NB + b) * PD * PD;
#pragma unroll
  for (int i = 0; i < 6; ++i) {
    int rowb = m0 + i * 16 + ((l >> 4) << 2);
#pragma unroll
    for (int r = 0; r < 4; ++r)
#pragma unroll
      for (int j = 0; j < 3; ++j)
        outp[(size_t)(rowb + r) * PD + n0 + j * 16 + (l & 15)] = acc[i][j][r];
  }
}

// ---------------- reduce partials + finalize covariance ----------------
__global__ __launch_bounds__(256) void reduce_fin_k(const float* __restrict__ partial,
                                                    const float* __restrict__ S,
                                                    float* __restrict__ G, int CH) {
  int e = blockIdx.x * 256 + threadIdx.x;
  const int tot = NB * PD * PD;
  if (e >= tot) return;
  int b = e / (PD * PD);
  int rem = e - b * PD * PD;
  int i = rem / PD, j = rem - i * PD;
  float s = 0.f;
  for (int c = 0; c < CH; ++c) s += partial[((size_t)c * NB + b) * PD * PD + rem];
  float mui = S[b * PD + i] * INV_N, muj = S[b * PD + j] * INV_N;
  G[e] = s * INV_N - mui * muj;
}

// ---------------- eigenvalues: register-resident Householder tridiag ----------------
// v7: 2 barriers/step. Matvec partials accumulated via ds_add_f32 into ppg[192]
// (+ v^T A v into one scalar); after B1 every wave computes w for its own 3 rows
// in registers (no wwg publish, no phase-B barrier). Update+prep fused, B2 ends step.
__global__ __launch_bounds__(768, 3) void eigen_k(const float* __restrict__ sigma,
                                                  float* __restrict__ out) {
  __shared__ float ppg[2][PD];      // matvec accumulator, double-buffered by parity
  __shared__ float vvg[2][PD];      // v, double-buffered, zero-padded below head
  __shared__ float red0[2];         // beta per parity
  __shared__ float red2s[2];        // v^T A v accumulator per parity
  __shared__ float dd[PD], ee[PD], e2[PD];
  __shared__ float sig[PD], csum[PD];
  __shared__ float grd[8];
  __shared__ float scanw[4];
  __shared__ int   redi[4];
  __shared__ int   cntb[4][PD];

  int b = blockIdx.x, t = threadIdx.x;
  int w = t >> 6, l = t & 63;
  int colbase = w << 4;
  const float* M = sigma + (size_t)b * PD * PD;

  // load fragment (strided f4 global reads; matrix is L2-resident)
  f4 a[3][4];
#pragma unroll
  for (int rr = 0; rr < 3; ++rr) {
    const float* mp = M + (size_t)((rr << 6) + l) * PD + colbase;
#pragma unroll
    for (int cc = 0; cc < 4; ++cc)
      a[rr][cc] = *(const f4*)(mp + (cc << 2));
  }
  if (t < PD) { ppg[0][t] = 0.f; ppg[1][t] = 0.f; }
  if (t == 0) { red2s[0] = 0.f; red2s[1] = 0.f; }

  // prep(c): owning wave extracts column c (span [c+1,PD)) from its (updated)
  // registers, computes alpha/beta, writes v/beta/ee.
  auto prep = [&](int c) {
    int wown = c >> 4;
    if (w == wown) {
      int k1 = c + 1;
      float av[3] = {0.f, 0.f, 0.f};
#pragma unroll
      for (int cc = 0; cc < 4; ++cc)
#pragma unroll
        for (int e = 0; e < 4; ++e) {
          if (colbase + (cc << 2) + e == c) {   // wave-uniform guard
            av[0] = a[0][cc][e]; av[1] = a[1][cc][e]; av[2] = a[2][cc][e];
          }
        }
      float am[3];
#pragma unroll
      for (int rr = 0; rr < 3; ++rr) {
        int row = (rr << 6) + l;
        am[rr] = (row >= k1) ? av[rr] : 0.f;
      }
      float sq = wave_sum(am[0] * am[0] + am[1] * am[1] + am[2] * am[2]);
      int slot2 = k1 >> 6;                       // uniform
      float tmp = (slot2 == 0) ? av[0] : (slot2 == 1) ? av[1] : av[2];
      float x0 = rdlane(tmp, k1 & 63);
      float nrm = sqrtf(sq);
      float alpha = (x0 >= 0.f) ? -nrm : nrm;
      bool degen = (sq < 1e-32f);
      float beta = degen ? 0.f : 1.0f / (sq - alpha * x0);
      if (l == 0) {
        red0[c & 1] = beta;
        ee[c] = degen ? x0 : alpha;
      }
      float head = x0 - alpha;
#pragma unroll
      for (int rr = 0; rr < 3; ++rr) {
        int row = (rr << 6) + l;
        vvg[c & 1][row] = (row < k1) ? 0.f : (row == k1) ? head : am[rr];
      }
    }
  };

  prep(0);
  __syncthreads();

  int slot = w >> 2;                 // wave-uniform register-slot of own cols
  int lbase = (w & 3) << 4;

  for (int k = 0; k < PD - 2; ++k) {
    int cur = k & 1, nxt = cur ^ 1;
    int k1 = k + 1;
    bool wact = (colbase + 15) >= k1;           // wave-uniform col retirement

    float vr[3] = {0.f, 0.f, 0.f};
    float sv[16];

    // ---- Phase A: ds_add partial p into ppg[cur]; dp into red2s[cur] ----
    if (wact) {
#pragma unroll
      for (int rr = 0; rr < 3; ++rr) vr[rr] = vvg[cur][(rr << 6) + l];
      {
        float src = (slot == 0) ? vr[0] : (slot == 1) ? vr[1] : vr[2];
#pragma unroll
        for (int j = 0; j < 16; ++j) sv[j] = rdlane(src, lbase + j);
      }
      float dp = 0.f;
#pragma unroll
      for (int rr = 0; rr < 3; ++rr) {
        if ((rr << 6) + 63 >= k1) {              // row-block retirement
          f4 s4 = {0.f, 0.f, 0.f, 0.f};
#pragma unroll
          for (int cc = 0; cc < 4; ++cc) {
            f4 sva = {sv[(cc << 2)], sv[(cc << 2) + 1], sv[(cc << 2) + 2], sv[(cc << 2) + 3]};
            s4 += sva * a[rr][cc];
          }
          float s = (s4.x + s4.y) + (s4.z + s4.w);
          atomicAdd(&ppg[cur][(rr << 6) + l], s);
          dp += vr[rr] * s;
        }
      }
      float dpt = wave_sum(dp);
      if (l == 0) atomicAdd(&red2s[cur], dpt);
    }
    if (w == 11) {                               // zero next-parity accumulators
      ppg[nxt][l] = 0.f; ppg[nxt][l + 64] = 0.f; ppg[nxt][l + 128] = 0.f;
      if (l == 0) red2s[nxt] = 0.f;
    }
    __syncthreads();                             // B1

    // ---- Phase BC: w in-register (own 3 rows), rank-2 update, prep next ----
    if (wact) {
      float beta = red0[cur];
      float vt = red2s[cur];
      float Kc = 0.5f * beta * beta * vt;
      float wreg[3], wj[16];
#pragma unroll
      for (int rr = 0; rr < 3; ++rr) {
        int row = (rr << 6) + l;
        float p = ppg[cur][row];
        wreg[rr] = (row >= k1) ? (beta * p - Kc * vr[rr]) : 0.f;
      }
      {
        float srcw = (slot == 0) ? wreg[0] : (slot == 1) ? wreg[1] : wreg[2];
#pragma unroll
        for (int j = 0; j < 16; ++j) wj[j] = rdlane(srcw, lbase + j);
      }
#pragma unroll
      for (int rr = 0; rr < 3; ++rr) {
        if ((rr << 6) + 63 >= k1) {
          float vrr = vr[rr], wrr = wreg[rr];
#pragma unroll
          for (int cc = 0; cc < 4; ++cc)
#pragma unroll
            for (int e = 0; e < 4; ++e) {
              int j = (cc << 2) + e;
              a[rr][cc][e] -= vrr * wj[j] + wrr * sv[j];
            }
        }
      }
    }
    prep(k + 1);                                 // owner wave is always col-active
    __syncthreads();                             // B2
  }

  // ---- extract diagonal ----
#pragma unroll
  for (int rr = 0; rr < 3; ++rr) {
    int row = (rr << 6) + l;
#pragma unroll
    for (int cc = 0; cc < 4; ++cc)
#pragma unroll
      for (int e = 0; e < 4; ++e)
        if (colbase + (cc << 2) + e == row) dd[row] = a[rr][cc][e];
  }
  __syncthreads();

  if (t < PD - 1) e2[t] = ee[t] * ee[t];

  // Gershgorin bounds
  float glo = 1e30f, ghi = -1e30f;
  if (t < PD) {
    float r = 0.f;
    if (t > 0) r += fabsf(ee[t - 1]);
    if (t < PD - 1) r += fabsf(ee[t]);
    glo = dd[t] - r;
    ghi = dd[t] + r;
  }
#pragma unroll
  for (int off = 32; off; off >>= 1) {
    glo = fminf(glo, __shfl_xor(glo, off, 64));
    ghi = fmaxf(ghi, __shfl_xor(ghi, off, 64));
  }
  if (l == 0 && w < 3) { grd[w] = glo; grd[4 + w] = ghi; }
  __syncthreads();
  float gl = fminf(grd[0], fminf(grd[1], grd[2]));
  float gh = fmaxf(grd[4], fmaxf(grd[5], grd[6]));
  float wid = gh - gl;
  gl -= 1e-3f * wid + 1e-20f;
  gh += 1e-3f * wid + 1e-20f;

  // ---- 5-ary Sturm bisection: 4 probe threads per eigenvalue ----
  {
    int we3 = w - (w / 3) * 3;                  // w % 3
    int sub = w / 3;                            // 0..3
    int e = (we3 << 6) + l;                     // eigenvalue index 0..191
    float lo = gl, hi = gh;
    for (int round = 0; round < 14; ++round) {
      float width = hi - lo;
      float xm = lo + width * (0.2f * (float)(sub + 1));
      int cnt = 0;
      float q = 1.0f;
      for (int i = 0; i < PD; ++i) {
        float term = (i > 0) ? e2[i - 1] * __builtin_amdgcn_rcpf(q) : 0.0f;
        q = (dd[i] - xm) - term;
        cnt += (q < 0.f);
        float aq = fabsf(q);
        if (aq < 1e-30f) q = (q < 0.f) ? -1e-30f : 1e-30f;
      }
      cntb[sub][e] = cnt;
      __syncthreads();
      int c0 = cntb[0][e], c1 = cntb[1][e], c2 = cntb[2][e], c3 = cntb[3][e];
      float mA = lo + width * 0.2f, mB = lo + width * 0.4f;
      float mC = lo + width * 0.6f, mD = lo + width * 0.8f;
      float nl = lo, nh = hi;
      if (c0 <= e) nl = mA;
      if (c1 <= e) nl = mB;
      if (c2 <= e) nl = mC;
      if (c3 <= e) nl = mD;
      if (c3 > e) nh = mD;
      if (c2 > e) nh = mC;
      if (c1 > e) nh = mB;
      if (c0 > e) nh = mA;
      lo = nl; hi = nh;
      __syncthreads();
    }
    if (sub == 0) sig[e] = 0.5f * (lo + hi);
  }
  __syncthreads();

  // parallel inclusive scan of sig -> csum (threads<192)
  {
    float x = (t < PD) ? sig[t] : 0.f;
    float scn = x;
#pragma unroll
    for (int off = 1; off < 64; off <<= 1) {
      float u = __shfl_up(scn, off, 64);
      if (l >= off) scn += u;
    }
    if (l == 63 && w < 3) scanw[w] = scn;
    __syncthreads();
    if (t < PD) {
      float base = 0.f;
      if (w >= 1) base += scanw[0];
      if (w >= 2) base += scanw[1];
      csum[t] = scn + base;
    }
  }
  __syncthreads();

  // threshold search (mirror of the reference's vectorized loop)
  float tau = 0.f;
  int vk = 1 << 30;
  if (t < PD) {
    int L = PD - 1 - t;
    tau = (L > 0) ? csum[L - 1] / (float)L : 0.0f;
    int gt = 0, lt2 = 0;
    for (int j = 0; j < L; ++j) {
      float svv = sig[j];
      gt  += (svv > tau);
      lt2 += (svv < tau);
    }
    if (gt == lt2) vk = t;
  }
#pragma unroll
  for (int off = 32; off; off >>= 1) vk = min(vk, __shfl_xor(vk, off, 64));
  if (l == 0 && w < 3) redi[w] = vk;
  __syncthreads();
  if (t == 0) {
    int g = min(redi[0], min(redi[1], redi[2]));
    redi[3] = (g == (1 << 30)) ? 0 : g;   // reference: argmax of all-false = 0
  }
  __syncthreads();
  if (t < PD && t == redi[3]) out[b] = sqrtf(fmaxf(tau, 0.f));
}

extern "C" void kernel_launch(void* const* d_in, const int* in_sizes, int n_in,
                              void* d_out, int out_size, void* d_ws, size_t ws_size,
                              hipStream_t stream) {
  const float* x = (const float*)d_in[0];
  float* out = (float*)d_out;

  size_t gElems = (size_t)NB * PD * PD;       // 294912
  int CH = 32;
  while (CH > 1 && ws_size < ((size_t)CH + 1) * gElems * 4 + (size_t)NB * PD * 4)
    CH >>= 1;
  float* G = (float*)d_ws;
  float* partial = G + gElems;
  float* S = partial + (size_t)CH * gElems;
  int chunkSize = (NPATCH + CH - 1) / CH;

  row_sums_k<<<NB * PD, 256, 0, stream>>>(x, S);
  cov_gemm_k<<<NB * CH, 512, 0, stream>>>(x, partial, CH, chunkSize);
  reduce_fin_k<<<(int)((gElems + 255) / 256), 256, 0, stream>>>(partial, S, G, CH);
  eigen_k<<<NB, 768, 0, stream>>>(G, out);
}